// Round 1
// baseline (792.360 us; speedup 1.0000x reference)
//
#include <hip/hip_runtime.h>
#include <cstdint>

#define NN 50000
#define NE 600000
#define NB 4

typedef unsigned short ushort_t;

// ---- workspace layout (float offsets) ----
// acc  : [NN][128] f32                          @ 0          (6,400,000 floats)
// H2   : [NN][128 cols][4 bases] bf16           @ 6,400,000  (25,600,000 ushorts = 12,800,000 floats)
// deg  : [NN] f32                               @ 19,200,000
// colsum/colsq : [128]+[128] f32                @ 19,250,000
#define ACC_OFF 0ul
#define H2_OFF  6400000ul
#define DEG_OFF 19200000ul
#define CS_OFF  19250000ul
#define CSQ_OFF 19250128ul

__device__ __forceinline__ float2 bf2_to_f2(uint32_t u) {
    float2 r;
    r.x = __uint_as_float(u << 16);
    r.y = __uint_as_float(u & 0xffff0000u);
    return r;
}

__device__ __forceinline__ ushort_t f2bf(float f) {
    uint32_t u = __float_as_uint(f);
    u = (u + 0x7fffu + ((u >> 16) & 1u)) >> 16;   // round-to-nearest-even
    return (ushort_t)u;
}

// ---------------------------------------------------------------------------
// K1: fused GEMM.  X[50000x128] @ [W_loop | B0 | B1 | B2 | B3] (128x640).
// seg 0 -> acc (f32, + b_loop); seg 1..4 -> H2 bf16 interleaved [node][col][base].
// Tile 64x64, 256 threads, 4x4/thread, K in two 64-chunks. LDS 2*64*68*4 = 34.8KB.
// ---------------------------------------------------------------------------
__global__ __launch_bounds__(256) void k_gemm(
    const float* __restrict__ X, const float* __restrict__ Wl,
    const float* __restrict__ bl, const float* __restrict__ bases,
    float* __restrict__ acc, ushort_t* __restrict__ H2)
{
    __shared__ float As[64][68];   // [row][k]  (k-contig: float4 loads along k)
    __shared__ float Bt[64][68];   // [col][k]  (transposed: float4 reads along k)

    const int tid = threadIdx.x;
    const int row0 = blockIdx.x * 64;
    const int nblk = blockIdx.y;          // 0..9
    const int seg = nblk >> 1;            // 0=selfloop, 1..4 = basis seg-1
    const int c0 = (nblk & 1) * 64;       // col offset within the 128-wide segment
    const float* __restrict__ B = (seg == 0) ? Wl : (bases + (size_t)(seg - 1) * 16384);

    const int tx = tid & 15, ty = tid >> 4;
    float accr[4][4];
#pragma unroll
    for (int i = 0; i < 4; ++i)
#pragma unroll
        for (int j = 0; j < 4; ++j) accr[i][j] = 0.f;

    for (int kb = 0; kb < 2; ++kb) {
        const int kbase = kb * 64;
        // load A chunk: 64 rows x 16 float4
#pragma unroll
        for (int it = 0; it < 4; ++it) {
            int l = tid + it * 256;
            int r = l >> 4;
            int k4 = (l & 15) << 2;
            int row = row0 + r;
            float4 v = make_float4(0.f, 0.f, 0.f, 0.f);
            if (row < NN) v = *(const float4*)(X + (size_t)row * 128 + kbase + k4);
            *(float4*)&As[r][k4] = v;
        }
        // load B chunk transposed: 64 k-rows x 16 float4
#pragma unroll
        for (int it = 0; it < 4; ++it) {
            int l = tid + it * 256;
            int k = l >> 4;
            int c4 = (l & 15) << 2;
            float4 v = *(const float4*)(B + (size_t)(kbase + k) * 128 + c0 + c4);
            Bt[c4 + 0][k] = v.x; Bt[c4 + 1][k] = v.y;
            Bt[c4 + 2][k] = v.z; Bt[c4 + 3][k] = v.w;
        }
        __syncthreads();

#pragma unroll 4
        for (int k0 = 0; k0 < 64; k0 += 4) {
            float4 a[4], b[4];
#pragma unroll
            for (int i = 0; i < 4; ++i) a[i] = *(const float4*)&As[ty * 4 + i][k0];
#pragma unroll
            for (int j = 0; j < 4; ++j) b[j] = *(const float4*)&Bt[tx + 16 * j][k0];
#pragma unroll
            for (int i = 0; i < 4; ++i)
#pragma unroll
                for (int j = 0; j < 4; ++j) {
                    accr[i][j] = fmaf(a[i].x, b[j].x, accr[i][j]);
                    accr[i][j] = fmaf(a[i].y, b[j].y, accr[i][j]);
                    accr[i][j] = fmaf(a[i].z, b[j].z, accr[i][j]);
                    accr[i][j] = fmaf(a[i].w, b[j].w, accr[i][j]);
                }
        }
        __syncthreads();
    }

    // store
#pragma unroll
    for (int i = 0; i < 4; ++i) {
        int row = row0 + ty * 4 + i;
        if (row < NN) {
#pragma unroll
            for (int j = 0; j < 4; ++j) {
                int c = c0 + tx + 16 * j;
                float v = accr[i][j];
                if (seg == 0) {
                    acc[(size_t)row * 128 + c] = v + bl[c];
                } else {
                    H2[((size_t)row * 128 + c) * 4 + (seg - 1)] = f2bf(v);
                }
            }
        }
    }
}

// ---------------------------------------------------------------------------
// K2: edge scatter. One wave per edge (grid-stride). Lane handles 2 cols.
// One coalesced uint4 (16B) load per lane = 1KB per edge (all 4 bases).
// ---------------------------------------------------------------------------
__global__ __launch_bounds__(256) void k_edges(
    const ushort_t* __restrict__ H2, const int* __restrict__ eidx,
    const int* __restrict__ etype, const float* __restrict__ coeff,
    float* __restrict__ acc, float* __restrict__ deg)
{
    const int lane = threadIdx.x & 63;
    const int wave = (blockIdx.x * blockDim.x + threadIdx.x) >> 6;
    const int nw = (gridDim.x * blockDim.x) >> 6;
    const int* __restrict__ src = eidx;
    const int* __restrict__ dst = eidx + NE;

    for (int e = wave; e < NE; e += nw) {
        const int s = src[e], d = dst[e], t = etype[e];
        const float cw0 = coeff[t * 4 + 0], cw1 = coeff[t * 4 + 1],
                    cw2 = coeff[t * 4 + 2], cw3 = coeff[t * 4 + 3];
        // 8 ushorts: {col0:b0,b1,b2,b3, col1:b0,b1,b2,b3}
        const uint4 hv = *(const uint4*)(H2 + ((size_t)s * 128 + lane * 2) * 4);
        const float2 p0 = bf2_to_f2(hv.x);   // col0 b0,b1
        const float2 p1 = bf2_to_f2(hv.y);   // col0 b2,b3
        const float2 p2 = bf2_to_f2(hv.z);   // col1 b0,b1
        const float2 p3 = bf2_to_f2(hv.w);   // col1 b2,b3
        const float mx = cw0 * p0.x + cw1 * p0.y + cw2 * p1.x + cw3 * p1.y;
        const float my = cw0 * p2.x + cw1 * p2.y + cw2 * p3.x + cw3 * p3.y;
        float* p = acc + (size_t)d * 128 + lane * 2;
        atomicAdd(p, mx);
        atomicAdd(p + 1, my);
        if (lane == 0) atomicAdd(deg + d, 1.0f);
    }
}

// ---------------------------------------------------------------------------
// K3: degree-normalize, write out, accumulate per-column sum/sumsq.
// Each thread owns one column (col = gtid & 127) across a row stripe.
// ---------------------------------------------------------------------------
__global__ __launch_bounds__(256) void k_norm_stats(
    const float* __restrict__ acc, const float* __restrict__ deg,
    float* __restrict__ out, float* __restrict__ colsum, float* __restrict__ colsq)
{
    const int tid = threadIdx.x;
    const int g = blockIdx.x * 256 + tid;
    const int col = g & 127;
    const int rstep = (gridDim.x * 256) >> 7;
    float s = 0.f, q = 0.f;
    for (int r = g >> 7; r < NN; r += rstep) {
        const float inv = 1.0f / fmaxf(deg[r], 1.0f);
        const float v = acc[(size_t)r * 128 + col] * inv;
        out[(size_t)r * 128 + col] = v;
        s += v; q += v * v;
    }
    __shared__ float s1[256], s2[256];
    s1[tid] = s; s2[tid] = q;
    __syncthreads();
    if (tid < 128) {
        atomicAdd(colsum + tid, s1[tid] + s1[tid + 128]);
        atomicAdd(colsq + tid, s2[tid] + s2[tid + 128]);
    }
}

// ---------------------------------------------------------------------------
// K4: BatchNorm (batch stats) + ReLU, in place on d_out.
// ---------------------------------------------------------------------------
__global__ __launch_bounds__(256) void k_bn_relu(
    float* __restrict__ out, const float* __restrict__ colsum,
    const float* __restrict__ colsq, const float* __restrict__ gamma,
    const float* __restrict__ beta)
{
    __shared__ float sc[128], sh[128];
    const int tid = threadIdx.x;
    if (tid < 128) {
        const float mean = colsum[tid] * (1.0f / NN);
        const float var = colsq[tid] * (1.0f / NN) - mean * mean;
        const float g = gamma[tid] * rsqrtf(var + 1e-5f);
        sc[tid] = g;
        sh[tid] = beta[tid] - mean * g;
    }
    __syncthreads();
    const int total = NN * 32;   // float4 count
    for (int i = blockIdx.x * 256 + tid; i < total; i += gridDim.x * 256) {
        const int c = (i & 31) << 2;
        float4 v = *(float4*)(out + (size_t)i * 4);
        v.x = fmaxf(fmaf(v.x, sc[c + 0], sh[c + 0]), 0.f);
        v.y = fmaxf(fmaf(v.y, sc[c + 1], sh[c + 1]), 0.f);
        v.z = fmaxf(fmaf(v.z, sc[c + 2], sh[c + 2]), 0.f);
        v.w = fmaxf(fmaf(v.w, sc[c + 3], sh[c + 3]), 0.f);
        *(float4*)(out + (size_t)i * 4) = v;
    }
}

extern "C" void kernel_launch(void* const* d_in, const int* in_sizes, int n_in,
                              void* d_out, int out_size, void* d_ws, size_t ws_size,
                              hipStream_t stream)
{
    const float* X      = (const float*)d_in[0];   // entity_emb [50000,128]
    const float* bases  = (const float*)d_in[1];   // [4,128,128]
    const float* coeff  = (const float*)d_in[2];   // [32,4]
    const float* Wl     = (const float*)d_in[3];   // [128,128]
    const float* bl     = (const float*)d_in[4];   // [128]
    const float* gamma  = (const float*)d_in[5];   // [128]
    const float* beta   = (const float*)d_in[6];   // [128]
    const int*   eidx   = (const int*)d_in[7];     // [2,600000]
    const int*   etype  = (const int*)d_in[8];     // [600000]
    float* out = (float*)d_out;

    float* ws = (float*)d_ws;
    float*    acc    = ws + ACC_OFF;
    ushort_t* H2     = (ushort_t*)(ws + H2_OFF);
    float*    deg    = ws + DEG_OFF;
    float*    colsum = ws + CS_OFF;
    float*    colsq  = ws + CSQ_OFF;

    // zero deg + colsum + colsq (contiguous: 50000 + 256 floats)
    hipMemsetAsync(deg, 0, (50000 + 256) * sizeof(float), stream);

    dim3 ggrid(782, 10);   // ceil(50000/64) x (640/64)
    k_gemm<<<ggrid, 256, 0, stream>>>(X, Wl, bl, bases, acc, H2);
    k_edges<<<2048, 256, 0, stream>>>(H2, eidx, etype, coeff, acc, deg);
    k_norm_stats<<<512, 256, 0, stream>>>(acc, deg, out, colsum, colsq);
    k_bn_relu<<<1024, 256, 0, stream>>>(out, colsum, colsq, gamma, beta);
}

// Round 2
// 417.970 us; speedup vs baseline: 1.8957x; 1.8957x over previous
//
#include <hip/hip_runtime.h>
#include <cstdint>

#define NN 50000
#define NE 600000
#define NB 4

typedef unsigned short ushort_t;

// ---- workspace layout (float offsets) ----
// acc  : [NN][128] f32                          @ 0           (6,400,000)
// H2   : [NN][128 cols][4 bases] bf16           @ 6,400,000   (12,800,000 floats worth)
// cnt  : [NN] i32                               @ 19,200,000
// curs : [NN] i32                               @ 19,250,000
// bsum : [128] i32                              @ 19,300,000
// bscan: [128] i32                              @ 19,300,128
// colsum/colsq : [128]+[128] f32                @ 19,300,256 / 19,300,384
// epack: [NE] u32  -> lives in d_out (only needed scatter->gather window)
#define ACC_OFF  0ul
#define H2_OFF   6400000ul
#define CNT_OFF  19200000ul
#define CUR_OFF  19250000ul
#define BSUM_OFF 19300000ul
#define BSCN_OFF 19300128ul
#define CS_OFF   19300256ul
#define CSQ_OFF  19300384ul

__device__ __forceinline__ float2 bf2_to_f2(uint32_t u) {
    float2 r;
    r.x = __uint_as_float(u << 16);
    r.y = __uint_as_float(u & 0xffff0000u);
    return r;
}

__device__ __forceinline__ ushort_t f2bf(float f) {
    uint32_t u = __float_as_uint(f);
    u = (u + 0x7fffu + ((u >> 16) & 1u)) >> 16;   // round-to-nearest-even
    return (ushort_t)u;
}

// ---------------------------------------------------------------------------
// K1: fused GEMM.  X[50000x128] @ [W_loop | B0 | B1 | B2 | B3] (128x640).
// seg 0 -> acc (f32, + b_loop); seg 1..4 -> H2 bf16 interleaved [node][col][base].
// ---------------------------------------------------------------------------
__global__ __launch_bounds__(256) void k_gemm(
    const float* __restrict__ X, const float* __restrict__ Wl,
    const float* __restrict__ bl, const float* __restrict__ bases,
    float* __restrict__ acc, ushort_t* __restrict__ H2)
{
    __shared__ float As[64][68];
    __shared__ float Bt[64][68];

    const int tid = threadIdx.x;
    const int row0 = blockIdx.x * 64;
    const int nblk = blockIdx.y;
    const int seg = nblk >> 1;
    const int c0 = (nblk & 1) * 64;
    const float* __restrict__ B = (seg == 0) ? Wl : (bases + (size_t)(seg - 1) * 16384);

    const int tx = tid & 15, ty = tid >> 4;
    float accr[4][4];
#pragma unroll
    for (int i = 0; i < 4; ++i)
#pragma unroll
        for (int j = 0; j < 4; ++j) accr[i][j] = 0.f;

    for (int kb = 0; kb < 2; ++kb) {
        const int kbase = kb * 64;
#pragma unroll
        for (int it = 0; it < 4; ++it) {
            int l = tid + it * 256;
            int r = l >> 4;
            int k4 = (l & 15) << 2;
            int row = row0 + r;
            float4 v = make_float4(0.f, 0.f, 0.f, 0.f);
            if (row < NN) v = *(const float4*)(X + (size_t)row * 128 + kbase + k4);
            *(float4*)&As[r][k4] = v;
        }
#pragma unroll
        for (int it = 0; it < 4; ++it) {
            int l = tid + it * 256;
            int k = l >> 4;
            int c4 = (l & 15) << 2;
            float4 v = *(const float4*)(B + (size_t)(kbase + k) * 128 + c0 + c4);
            Bt[c4 + 0][k] = v.x; Bt[c4 + 1][k] = v.y;
            Bt[c4 + 2][k] = v.z; Bt[c4 + 3][k] = v.w;
        }
        __syncthreads();

#pragma unroll 4
        for (int k0 = 0; k0 < 64; k0 += 4) {
            float4 a[4], b[4];
#pragma unroll
            for (int i = 0; i < 4; ++i) a[i] = *(const float4*)&As[ty * 4 + i][k0];
#pragma unroll
            for (int j = 0; j < 4; ++j) b[j] = *(const float4*)&Bt[tx + 16 * j][k0];
#pragma unroll
            for (int i = 0; i < 4; ++i)
#pragma unroll
                for (int j = 0; j < 4; ++j) {
                    accr[i][j] = fmaf(a[i].x, b[j].x, accr[i][j]);
                    accr[i][j] = fmaf(a[i].y, b[j].y, accr[i][j]);
                    accr[i][j] = fmaf(a[i].z, b[j].z, accr[i][j]);
                    accr[i][j] = fmaf(a[i].w, b[j].w, accr[i][j]);
                }
        }
        __syncthreads();
    }

#pragma unroll
    for (int i = 0; i < 4; ++i) {
        int row = row0 + ty * 4 + i;
        if (row < NN) {
#pragma unroll
            for (int j = 0; j < 4; ++j) {
                int c = c0 + tx + 16 * j;
                float v = accr[i][j];
                if (seg == 0) {
                    acc[(size_t)row * 128 + c] = v + bl[c];
                } else {
                    H2[((size_t)row * 128 + c) * 4 + (seg - 1)] = f2bf(v);
                }
            }
        }
    }
}

// ---------------------------------------------------------------------------
// K2: histogram of dst -> cnt
// ---------------------------------------------------------------------------
__global__ __launch_bounds__(256) void k_hist(
    const int* __restrict__ eidx, int* __restrict__ cnt)
{
    const int* __restrict__ dst = eidx + NE;
    for (int e = blockIdx.x * 256 + threadIdx.x; e < NE; e += gridDim.x * 256)
        atomicAdd(cnt + dst[e], 1);
}

// ---------------------------------------------------------------------------
// K3a: per-block exclusive scan (512 elems/block, 256 thr) -> curs, bsum
// ---------------------------------------------------------------------------
__global__ __launch_bounds__(256) void k_scan1(
    const int* __restrict__ cnt, int* __restrict__ curs, int* __restrict__ bsum)
{
    __shared__ int sh[256];
    const int tid = threadIdx.x;
    const int i0 = blockIdx.x * 512 + tid * 2;
    const int v0 = (i0 < NN) ? cnt[i0] : 0;
    const int v1 = (i0 + 1 < NN) ? cnt[i0 + 1] : 0;
    int s = v0 + v1;
    sh[tid] = s;
    __syncthreads();
#pragma unroll
    for (int off = 1; off < 256; off <<= 1) {
        int t = (tid >= off) ? sh[tid - off] : 0;
        __syncthreads();
        sh[tid] += t;
        __syncthreads();
    }
    const int excl = sh[tid] - s;      // exclusive base for this pair
    if (i0 < NN) curs[i0] = excl;
    if (i0 + 1 < NN) curs[i0 + 1] = excl + v0;
    if (tid == 255) bsum[blockIdx.x] = sh[255];
}

// ---------------------------------------------------------------------------
// K3b: scan of 98 block sums -> bscan (exclusive). One block, 128 threads.
// ---------------------------------------------------------------------------
__global__ __launch_bounds__(128) void k_scan2(
    const int* __restrict__ bsum, int* __restrict__ bscan, int nblk)
{
    __shared__ int sh[128];
    const int tid = threadIdx.x;
    int v = (tid < nblk) ? bsum[tid] : 0;
    sh[tid] = v;
    __syncthreads();
#pragma unroll
    for (int off = 1; off < 128; off <<= 1) {
        int t = (tid >= off) ? sh[tid - off] : 0;
        __syncthreads();
        sh[tid] += t;
        __syncthreads();
    }
    if (tid < nblk) bscan[tid] = sh[tid] - v;
}

// ---------------------------------------------------------------------------
// K3c: add back -> final exclusive offsets in curs
// ---------------------------------------------------------------------------
__global__ __launch_bounds__(256) void k_scan3(
    int* __restrict__ curs, const int* __restrict__ bscan)
{
    const int add = bscan[blockIdx.x];
    const int i0 = blockIdx.x * 512 + threadIdx.x * 2;
    if (i0 < NN) curs[i0] += add;
    if (i0 + 1 < NN) curs[i0 + 1] += add;
}

// ---------------------------------------------------------------------------
// K4: scatter edges into CSR slots. epack = src | (type<<16).
// After this kernel curs[d] == end offset of node d.
// ---------------------------------------------------------------------------
__global__ __launch_bounds__(256) void k_scatter(
    const int* __restrict__ eidx, const int* __restrict__ etype,
    int* __restrict__ curs, uint32_t* __restrict__ epack)
{
    const int* __restrict__ src = eidx;
    const int* __restrict__ dst = eidx + NE;
    for (int e = blockIdx.x * 256 + threadIdx.x; e < NE; e += gridDim.x * 256) {
        const int d = dst[e];
        const int pos = atomicAdd(curs + d, 1);
        epack[pos] = (uint32_t)src[e] | ((uint32_t)etype[e] << 16);
    }
}

// ---------------------------------------------------------------------------
// K5: gather. One wave per dst node, 2 cols/lane, zero atomics.
// Folds self-loop + message sum + degree normalization; writes acc in place.
// ---------------------------------------------------------------------------
__global__ __launch_bounds__(256) void k_gather(
    const ushort_t* __restrict__ H2, const uint32_t* __restrict__ epack,
    const int* __restrict__ cnt, const int* __restrict__ curs,
    const float* __restrict__ coeff, float* __restrict__ acc)
{
    const int lane = threadIdx.x & 63;
    const int d = (blockIdx.x * 256 + threadIdx.x) >> 6;
    if (d >= NN) return;

    const int n = cnt[d];
    const int end = curs[d];          // post-scatter: end offset
    const int start = end - n;

    float m0 = 0.f, m1 = 0.f;
    uint32_t ep = (n > 0) ? epack[start] : 0u;
    for (int j = 0; j < n; ++j) {
        const uint32_t cur = ep;
        if (j + 1 < n) ep = epack[start + j + 1];
        const int s = cur & 0xffff;
        const int t = cur >> 16;
        const float4 cw = *(const float4*)(coeff + t * 4);
        const uint4 hv = *(const uint4*)(H2 + ((size_t)s * 128 + lane * 2) * 4);
        const float2 p0 = bf2_to_f2(hv.x);
        const float2 p1 = bf2_to_f2(hv.y);
        const float2 p2 = bf2_to_f2(hv.z);
        const float2 p3 = bf2_to_f2(hv.w);
        m0 += cw.x * p0.x + cw.y * p0.y + cw.z * p1.x + cw.w * p1.y;
        m1 += cw.x * p2.x + cw.y * p2.y + cw.z * p3.x + cw.w * p3.y;
    }

    const float inv = 1.0f / (float)((n > 0) ? n : 1);
    float* p = acc + (size_t)d * 128 + lane * 2;
    float2 a = *(float2*)p;
    a.x = (a.x + m0) * inv;
    a.y = (a.y + m1) * inv;
    *(float2*)p = a;
}

// ---------------------------------------------------------------------------
// K6: copy acc -> out, accumulate per-column sum/sumsq.
// ---------------------------------------------------------------------------
__global__ __launch_bounds__(256) void k_stats(
    const float* __restrict__ acc, float* __restrict__ out,
    float* __restrict__ colsum, float* __restrict__ colsq)
{
    const int tid = threadIdx.x;
    const int g = blockIdx.x * 256 + tid;
    const int col = g & 127;
    const int rstep = (gridDim.x * 256) >> 7;
    float s = 0.f, q = 0.f;
    for (int r = g >> 7; r < NN; r += rstep) {
        const float v = acc[(size_t)r * 128 + col];
        out[(size_t)r * 128 + col] = v;
        s += v; q += v * v;
    }
    __shared__ float s1[256], s2[256];
    s1[tid] = s; s2[tid] = q;
    __syncthreads();
    if (tid < 128) {
        atomicAdd(colsum + tid, s1[tid] + s1[tid + 128]);
        atomicAdd(colsq + tid, s2[tid] + s2[tid + 128]);
    }
}

// ---------------------------------------------------------------------------
// K7: BatchNorm (batch stats) + ReLU, in place on d_out.
// ---------------------------------------------------------------------------
__global__ __launch_bounds__(256) void k_bn_relu(
    float* __restrict__ out, const float* __restrict__ colsum,
    const float* __restrict__ colsq, const float* __restrict__ gamma,
    const float* __restrict__ beta)
{
    __shared__ float sc[128], sh[128];
    const int tid = threadIdx.x;
    if (tid < 128) {
        const float mean = colsum[tid] * (1.0f / NN);
        const float var = colsq[tid] * (1.0f / NN) - mean * mean;
        const float g = gamma[tid] * rsqrtf(var + 1e-5f);
        sc[tid] = g;
        sh[tid] = beta[tid] - mean * g;
    }
    __syncthreads();
    const int total = NN * 32;
    for (int i = blockIdx.x * 256 + tid; i < total; i += gridDim.x * 256) {
        const int c = (i & 31) << 2;
        float4 v = *(float4*)(out + (size_t)i * 4);
        v.x = fmaxf(fmaf(v.x, sc[c + 0], sh[c + 0]), 0.f);
        v.y = fmaxf(fmaf(v.y, sc[c + 1], sh[c + 1]), 0.f);
        v.z = fmaxf(fmaf(v.z, sc[c + 2], sh[c + 2]), 0.f);
        v.w = fmaxf(fmaf(v.w, sc[c + 3], sh[c + 3]), 0.f);
        *(float4*)(out + (size_t)i * 4) = v;
    }
}

extern "C" void kernel_launch(void* const* d_in, const int* in_sizes, int n_in,
                              void* d_out, int out_size, void* d_ws, size_t ws_size,
                              hipStream_t stream)
{
    const float* X      = (const float*)d_in[0];
    const float* bases  = (const float*)d_in[1];
    const float* coeff  = (const float*)d_in[2];
    const float* Wl     = (const float*)d_in[3];
    const float* bl     = (const float*)d_in[4];
    const float* gamma  = (const float*)d_in[5];
    const float* beta   = (const float*)d_in[6];
    const int*   eidx   = (const int*)d_in[7];
    const int*   etype  = (const int*)d_in[8];
    float* out = (float*)d_out;

    float* ws = (float*)d_ws;
    float*    acc    = ws + ACC_OFF;
    ushort_t* H2     = (ushort_t*)(ws + H2_OFF);
    int*      cnt    = (int*)(ws + CNT_OFF);
    int*      curs   = (int*)(ws + CUR_OFF);
    int*      bsum   = (int*)(ws + BSUM_OFF);
    int*      bscan  = (int*)(ws + BSCN_OFF);
    float*    colsum = ws + CS_OFF;
    float*    colsq  = ws + CSQ_OFF;
    uint32_t* epack  = (uint32_t*)d_out;   // transient: scatter -> gather window

    // zero cnt..colsq range (covers cnt, curs, bsum, bscan, colsum, colsq)
    hipMemsetAsync(cnt, 0, (CSQ_OFF + 128 - CNT_OFF) * sizeof(float), stream);

    const int nblk_scan = (NN + 511) / 512;   // 98

    dim3 ggrid(782, 10);
    k_gemm<<<ggrid, 256, 0, stream>>>(X, Wl, bl, bases, acc, H2);
    k_hist<<<512, 256, 0, stream>>>(eidx, cnt);
    k_scan1<<<nblk_scan, 256, 0, stream>>>(cnt, curs, bsum);
    k_scan2<<<1, 128, 0, stream>>>(bsum, bscan, nblk_scan);
    k_scan3<<<nblk_scan, 256, 0, stream>>>(curs, bscan);
    k_scatter<<<512, 256, 0, stream>>>(eidx, etype, curs, epack);
    k_gather<<<(NN + 3) / 4, 256, 0, stream>>>(H2, epack, cnt, curs, coeff, acc);
    k_stats<<<512, 256, 0, stream>>>(acc, out, colsum, colsq);
    k_bn_relu<<<1024, 256, 0, stream>>>(out, colsum, colsq, gamma, beta);
}

// Round 5
// 370.981 us; speedup vs baseline: 2.1358x; 1.1267x over previous
//
#include <hip/hip_runtime.h>
#include <cstdint>

#define NN 50000
#define NE 600000

typedef unsigned short ushort_t;
typedef __bf16 bf16_t;
typedef __attribute__((ext_vector_type(8))) bf16_t bf16x8;
typedef __attribute__((ext_vector_type(8))) ushort_t ushort8;
typedef __attribute__((ext_vector_type(4))) float f32x4;

// ---- workspace layout (float offsets) ----
// acc  : [NN][128] f32                        @ 0
// H2   : [NN][4 bases][128 cols] bf16         @ 6,400,000   (25.6M ushorts)
// cnt  : [NN] i32                             @ 19,200,000
// curs : [NN] i32                             @ 19,250,000
// bsum/bscan : [128]+[128] i32                @ 19,300,000 / 19,300,128
// colsum/colsq : [128]+[128] f32              @ 19,300,256 / 19,300,384
// ---- d_out transients (non-overlapping lifetimes) ----
// epack: [NE] u32   @ d_out float 0        (scatter -> gather window)
// WT   : [640][128] bf16 @ d_out float 700000  (prep -> gemm window)
#define ACC_OFF  0ul
#define H2_OFF   6400000ul
#define CNT_OFF  19200000ul
#define CUR_OFF  19250000ul
#define BSUM_OFF 19300000ul
#define BSCN_OFF 19300128ul
#define CS_OFF   19300256ul
#define CSQ_OFF  19300384ul
#define WT_OUT_OFF 700000ul

__device__ __forceinline__ float2 bf2_to_f2(uint32_t u) {
    float2 r;
    r.x = __uint_as_float(u << 16);         // low ushort  = even col
    r.y = __uint_as_float(u & 0xffff0000u); // high ushort = odd col
    return r;
}

__device__ __forceinline__ ushort_t f2bf(float f) {
    uint32_t u = __float_as_uint(f);
    u = (u + 0x7fffu + ((u >> 16) & 1u)) >> 16;   // RNE
    return (ushort_t)u;
}

// ---------------------------------------------------------------------------
// K0: build WT[n][k] bf16 = concat(W_loop | B0..B3) transposed. 81920 elems.
// WT[n*128+k] = Wcat[k][n]
// ---------------------------------------------------------------------------
__global__ __launch_bounds__(256) void k_prep(
    const float* __restrict__ Wl, const float* __restrict__ bases,
    ushort_t* __restrict__ WT)
{
    const int i = blockIdx.x * 256 + threadIdx.x;
    if (i >= 640 * 128) return;
    const int n = i >> 7, k = i & 127;
    float v;
    if (n < 128) v = Wl[k * 128 + n];
    else         v = bases[(size_t)((n >> 7) - 1) * 16384 + k * 128 + (n & 127)];
    WT[i] = f2bf(v);
}

// ---------------------------------------------------------------------------
// K1: bf16 MFMA GEMM using 16x16x32 fragment layouts:
//   A: m = lane&15, k = (lane>>4)*8 + j   (8 contiguous bf16 per lane)
//   B: n = lane&15, k = (lane>>4)*8 + j
//   D: col = lane&15, row = (lane>>4)*4 + reg
// Block = 32 rows x 640 cols (X fetched exactly once). 4 waves:
//   wave w -> row-half h=(w&1)*16, col-group cg=w>>1 (320 cols = 20 tiles).
// ---------------------------------------------------------------------------
__global__ __launch_bounds__(256) void k_gemm(
    const float* __restrict__ X, const ushort_t* __restrict__ WT,
    const float* __restrict__ bl, float* __restrict__ acc,
    ushort_t* __restrict__ H2)
{
    __shared__ ushort_t As[32][136];
    const int tid = threadIdx.x;
    const int row0 = blockIdx.x * 32;

    // stage: 32 rows x 128 f32 -> bf16 LDS. 8 threads/row, 16 floats each.
    {
        const int r = tid >> 3;
        const int c0 = (tid & 7) * 16;
        const int row = row0 + r;
        float4 v[4];
        if (row < NN) {
            const float4* p = (const float4*)(X + (size_t)row * 128 + c0);
            v[0] = p[0]; v[1] = p[1]; v[2] = p[2]; v[3] = p[3];
        } else {
            v[0] = v[1] = v[2] = v[3] = make_float4(0.f, 0.f, 0.f, 0.f);
        }
        ushort_t tmp[16];
#pragma unroll
        for (int i = 0; i < 4; ++i) {
            tmp[i * 4 + 0] = f2bf(((const float*)&v[i])[0]);
            tmp[i * 4 + 1] = f2bf(((const float*)&v[i])[1]);
            tmp[i * 4 + 2] = f2bf(((const float*)&v[i])[2]);
            tmp[i * 4 + 3] = f2bf(((const float*)&v[i])[3]);
        }
        // 16 ushorts = 32 bytes = TWO uint4 stores (round-3/4 bug: only one)
        *(uint4*)&As[r][c0]     = *(const uint4*)&tmp[0];
        *(uint4*)&As[r][c0 + 8] = *(const uint4*)&tmp[8];
    }
    __syncthreads();

    const int lane = tid & 63;
    const int w = tid >> 6;
    const int h = (w & 1) * 16;      // row-half base within block
    const int cg = w >> 1;           // col group: 0 -> cols 0..319, 1 -> 320..639
    const int m = lane & 15;
    const int quad = lane >> 4;

    // A fragments: 4 K-chunks of 32; lane holds 8 contiguous bf16 at quad*8
    bf16x8 afrag[4];
    const int arow = h + m;
#pragma unroll
    for (int kc = 0; kc < 4; ++kc)
        afrag[kc] = __builtin_bit_cast(bf16x8,
            *(const ushort8*)&As[arow][kc * 32 + quad * 8]);

    f32x4 c[20];
#pragma unroll
    for (int t = 0; t < 20; ++t)
#pragma unroll
        for (int i = 0; i < 4; ++i) c[t][i] = 0.f;

    // B base pointer for this lane's column n = c0 + m, k-offset quad*8
    const ushort_t* __restrict__ bbase =
        WT + ((size_t)(cg * 320 + m)) * 128 + quad * 8;

#pragma unroll
    for (int t = 0; t < 20; ++t) {
        const ushort_t* bp = bbase + (size_t)t * 16 * 128;
#pragma unroll
        for (int kc = 0; kc < 4; ++kc) {
            const bf16x8 bfr = __builtin_bit_cast(bf16x8,
                *(const ushort8*)(bp + kc * 32));
            c[t] = __builtin_amdgcn_mfma_f32_16x16x32_bf16(afrag[kc], bfr, c[t], 0, 0, 0);
        }
    }

    // epilogue. D: col = lane&15 (-> cb), row = quad*4 + reg
#pragma unroll
    for (int t = 0; t < 20; ++t) {
        const int c0 = cg * 320 + t * 16;
        const int seg = c0 >> 7;
        const int cb = (c0 & 127) + m;
        const int rowb = row0 + h + quad * 4;
        if (seg == 0) {
            const float blv = bl[cb];
#pragma unroll
            for (int r = 0; r < 4; ++r) {
                const int row = rowb + r;
                if (row < NN) acc[(size_t)row * 128 + cb] = c[t][r] + blv;
            }
        } else {
            const int b = seg - 1;
#pragma unroll
            for (int r = 0; r < 4; ++r) {
                const int row = rowb + r;
                if (row < NN) H2[(size_t)row * 512 + b * 128 + cb] = f2bf(c[t][r]);
            }
        }
    }
}

// ---------------------------------------------------------------------------
// K2: histogram of dst -> cnt
// ---------------------------------------------------------------------------
__global__ __launch_bounds__(256) void k_hist(
    const int* __restrict__ eidx, int* __restrict__ cnt)
{
    const int* __restrict__ dst = eidx + NE;
    for (int e = blockIdx.x * 256 + threadIdx.x; e < NE; e += gridDim.x * 256)
        atomicAdd(cnt + dst[e], 1);
}

// ---------------------------------------------------------------------------
// K3a/b/c: exclusive scan of cnt -> curs
// ---------------------------------------------------------------------------
__global__ __launch_bounds__(256) void k_scan1(
    const int* __restrict__ cnt, int* __restrict__ curs, int* __restrict__ bsum)
{
    __shared__ int sh[256];
    const int tid = threadIdx.x;
    const int i0 = blockIdx.x * 512 + tid * 2;
    const int v0 = (i0 < NN) ? cnt[i0] : 0;
    const int v1 = (i0 + 1 < NN) ? cnt[i0 + 1] : 0;
    int s = v0 + v1;
    sh[tid] = s;
    __syncthreads();
#pragma unroll
    for (int off = 1; off < 256; off <<= 1) {
        int t = (tid >= off) ? sh[tid - off] : 0;
        __syncthreads();
        sh[tid] += t;
        __syncthreads();
    }
    const int excl = sh[tid] - s;
    if (i0 < NN) curs[i0] = excl;
    if (i0 + 1 < NN) curs[i0 + 1] = excl + v0;
    if (tid == 255) bsum[blockIdx.x] = sh[255];
}

__global__ __launch_bounds__(128) void k_scan2(
    const int* __restrict__ bsum, int* __restrict__ bscan, int nblk)
{
    __shared__ int sh[128];
    const int tid = threadIdx.x;
    int v = (tid < nblk) ? bsum[tid] : 0;
    sh[tid] = v;
    __syncthreads();
#pragma unroll
    for (int off = 1; off < 128; off <<= 1) {
        int t = (tid >= off) ? sh[tid - off] : 0;
        __syncthreads();
        sh[tid] += t;
        __syncthreads();
    }
    if (tid < nblk) bscan[tid] = sh[tid] - v;
}

__global__ __launch_bounds__(256) void k_scan3(
    int* __restrict__ curs, const int* __restrict__ bscan)
{
    const int add = bscan[blockIdx.x];
    const int i0 = blockIdx.x * 512 + threadIdx.x * 2;
    if (i0 < NN) curs[i0] += add;
    if (i0 + 1 < NN) curs[i0 + 1] += add;
}

// ---------------------------------------------------------------------------
// K4: scatter edges into CSR slots. epack = src | (type<<16).
// ---------------------------------------------------------------------------
__global__ __launch_bounds__(256) void k_scatter(
    const int* __restrict__ eidx, const int* __restrict__ etype,
    int* __restrict__ curs, uint32_t* __restrict__ epack)
{
    const int* __restrict__ src = eidx;
    const int* __restrict__ dst = eidx + NE;
    for (int e = blockIdx.x * 256 + threadIdx.x; e < NE; e += gridDim.x * 256) {
        const int d = dst[e];
        const int pos = atomicAdd(curs + d, 1);
        epack[pos] = (uint32_t)src[e] | ((uint32_t)etype[e] << 16);
    }
}

// ---------------------------------------------------------------------------
// K5: gather. One wave per dst node, 2 cols/lane, zero atomics.
// H2 layout [node][base][col]: 4 dword loads per edge per lane.
// ---------------------------------------------------------------------------
__device__ __forceinline__ void edge_accum(
    uint32_t ep, const ushort_t* __restrict__ H2,
    const float* __restrict__ coeff, int lane, float& m0, float& m1)
{
    const int s = ep & 0xffff;
    const int t = ep >> 16;
    const float4 cw = *(const float4*)(coeff + t * 4);
    const ushort_t* hp = H2 + (size_t)s * 512 + lane * 2;
    const uint32_t v0 = *(const uint32_t*)(hp);
    const uint32_t v1 = *(const uint32_t*)(hp + 128);
    const uint32_t v2 = *(const uint32_t*)(hp + 256);
    const uint32_t v3 = *(const uint32_t*)(hp + 384);
    const float2 p0 = bf2_to_f2(v0);
    const float2 p1 = bf2_to_f2(v1);
    const float2 p2 = bf2_to_f2(v2);
    const float2 p3 = bf2_to_f2(v3);
    m0 += cw.x * p0.x + cw.y * p1.x + cw.z * p2.x + cw.w * p3.x;
    m1 += cw.x * p0.y + cw.y * p1.y + cw.z * p2.y + cw.w * p3.y;
}

__global__ __launch_bounds__(256) void k_gather(
    const ushort_t* __restrict__ H2, const uint32_t* __restrict__ epack,
    const int* __restrict__ cnt, const int* __restrict__ curs,
    const float* __restrict__ coeff, float* __restrict__ acc)
{
    const int lane = threadIdx.x & 63;
    const int d = (blockIdx.x * 256 + threadIdx.x) >> 6;
    if (d >= NN) return;

    const int n = cnt[d];
    const int end = curs[d];          // post-scatter: end offset
    int j = end - n;

    float m0 = 0.f, m1 = 0.f;
    for (; j + 1 < end; j += 2) {
        const uint32_t e0 = epack[j];
        const uint32_t e1 = epack[j + 1];
        edge_accum(e0, H2, coeff, lane, m0, m1);
        edge_accum(e1, H2, coeff, lane, m0, m1);
    }
    if (j < end) edge_accum(epack[j], H2, coeff, lane, m0, m1);

    const float inv = 1.0f / (float)((n > 0) ? n : 1);
    float* p = acc + (size_t)d * 128 + lane * 2;
    float2 a = *(float2*)p;
    a.x = (a.x + m0) * inv;
    a.y = (a.y + m1) * inv;
    *(float2*)p = a;
}

// ---------------------------------------------------------------------------
// K6: copy acc -> out, accumulate per-column sum/sumsq.
// ---------------------------------------------------------------------------
__global__ __launch_bounds__(256) void k_stats(
    const float* __restrict__ acc, float* __restrict__ out,
    float* __restrict__ colsum, float* __restrict__ colsq)
{
    const int tid = threadIdx.x;
    const int g = blockIdx.x * 256 + tid;
    const int col = g & 127;
    const int rstep = (gridDim.x * 256) >> 7;
    float s = 0.f, q = 0.f;
    for (int r = g >> 7; r < NN; r += rstep) {
        const float v = acc[(size_t)r * 128 + col];
        out[(size_t)r * 128 + col] = v;
        s += v; q += v * v;
    }
    __shared__ float s1[256], s2[256];
    s1[tid] = s; s2[tid] = q;
    __syncthreads();
    if (tid < 128) {
        atomicAdd(colsum + tid, s1[tid] + s1[tid + 128]);
        atomicAdd(colsq + tid, s2[tid] + s2[tid + 128]);
    }
}

// ---------------------------------------------------------------------------
// K7: BatchNorm (batch stats) + ReLU, in place on d_out.
// ---------------------------------------------------------------------------
__global__ __launch_bounds__(256) void k_bn_relu(
    float* __restrict__ out, const float* __restrict__ colsum,
    const float* __restrict__ colsq, const float* __restrict__ gamma,
    const float* __restrict__ beta)
{
    __shared__ float sc[128], sh[128];
    const int tid = threadIdx.x;
    if (tid < 128) {
        const float mean = colsum[tid] * (1.0f / NN);
        const float var = colsq[tid] * (1.0f / NN) - mean * mean;
        const float g = gamma[tid] * rsqrtf(var + 1e-5f);
        sc[tid] = g;
        sh[tid] = beta[tid] - mean * g;
    }
    __syncthreads();
    const int total = NN * 32;
    for (int i = blockIdx.x * 256 + tid; i < total; i += gridDim.x * 256) {
        const int c = (i & 31) << 2;
        float4 v = *(float4*)(out + (size_t)i * 4);
        v.x = fmaxf(fmaf(v.x, sc[c + 0], sh[c + 0]), 0.f);
        v.y = fmaxf(fmaf(v.y, sc[c + 1], sh[c + 1]), 0.f);
        v.z = fmaxf(fmaf(v.z, sc[c + 2], sh[c + 2]), 0.f);
        v.w = fmaxf(fmaf(v.w, sc[c + 3], sh[c + 3]), 0.f);
        *(float4*)(out + (size_t)i * 4) = v;
    }
}

extern "C" void kernel_launch(void* const* d_in, const int* in_sizes, int n_in,
                              void* d_out, int out_size, void* d_ws, size_t ws_size,
                              hipStream_t stream)
{
    const float* X      = (const float*)d_in[0];
    const float* bases  = (const float*)d_in[1];
    const float* coeff  = (const float*)d_in[2];
    const float* Wl     = (const float*)d_in[3];
    const float* bl     = (const float*)d_in[4];
    const float* gamma  = (const float*)d_in[5];
    const float* beta   = (const float*)d_in[6];
    const int*   eidx   = (const int*)d_in[7];
    const int*   etype  = (const int*)d_in[8];
    float* out = (float*)d_out;

    float* ws = (float*)d_ws;
    float*    acc    = ws + ACC_OFF;
    ushort_t* H2     = (ushort_t*)(ws + H2_OFF);
    int*      cnt    = (int*)(ws + CNT_OFF);
    int*      curs   = (int*)(ws + CUR_OFF);
    int*      bsum   = (int*)(ws + BSUM_OFF);
    int*      bscan  = (int*)(ws + BSCN_OFF);
    float*    colsum = ws + CS_OFF;
    float*    colsq  = ws + CSQ_OFF;
    uint32_t* epack  = (uint32_t*)d_out;                  // scatter->gather window
    ushort_t* WT     = (ushort_t*)(out + WT_OUT_OFF);     // prep->gemm window

    // zero cnt, curs, bsum, bscan, colsum, colsq
    hipMemsetAsync(cnt, 0, (CSQ_OFF + 128 - CNT_OFF) * sizeof(float), stream);

    const int nblk_scan = (NN + 511) / 512;   // 98

    k_prep<<<(640 * 128 + 255) / 256, 256, 0, stream>>>(Wl, bases, WT);
    k_gemm<<<(NN + 31) / 32, 256, 0, stream>>>(X, WT, bl, acc, H2);
    k_hist<<<512, 256, 0, stream>>>(eidx, cnt);
    k_scan1<<<nblk_scan, 256, 0, stream>>>(cnt, curs, bsum);
    k_scan2<<<1, 128, 0, stream>>>(bsum, bscan, nblk_scan);
    k_scan3<<<nblk_scan, 256, 0, stream>>>(curs, bscan);
    k_scatter<<<512, 256, 0, stream>>>(eidx, etype, curs, epack);
    k_gather<<<(NN + 3) / 4, 256, 0, stream>>>(H2, epack, cnt, curs, coeff, acc);
    k_stats<<<512, 256, 0, stream>>>(acc, out, colsum, colsq);
    k_bn_relu<<<1024, 256, 0, stream>>>(out, colsum, colsq, gamma, beta);
}

// Round 6
// 321.611 us; speedup vs baseline: 2.4637x; 1.1535x over previous
//
#include <hip/hip_runtime.h>
#include <cstdint>

#define NN 50000
#define NE 600000

typedef unsigned short ushort_t;
typedef __bf16 bf16_t;
typedef __attribute__((ext_vector_type(8))) bf16_t bf16x8;
typedef __attribute__((ext_vector_type(8))) ushort_t ushort8;
typedef __attribute__((ext_vector_type(4))) float f32x4;

// ---- workspace layout (float offsets) ----
// acc  : [NN][128] f32                        @ 0
// H2   : [NN][4 bases][128 cols] bf16         @ 6,400,000   (25.6M ushorts)
// cnt  : [NN] i32                             @ 19,200,000
// curs : [NN] i32                             @ 19,250,000
// bsum/bscan : [128]+[128] i32                @ 19,300,000 / 19,300,128
// colsum/colsq : [128]+[128] f32              @ 19,300,256 / 19,300,384
// ---- d_out transients (non-overlapping lifetimes) ----
// epack: [NE] u32   @ d_out float 0            (scatter -> gather window)
// WT   : [640][128] bf16 @ d_out float 700000  (prep -> gemm window)
#define ACC_OFF  0ul
#define H2_OFF   6400000ul
#define CNT_OFF  19200000ul
#define CUR_OFF  19250000ul
#define BSUM_OFF 19300000ul
#define BSCN_OFF 19300128ul
#define CS_OFF   19300256ul
#define CSQ_OFF  19300384ul
#define WT_OUT_OFF 700000ul

__device__ __forceinline__ float2 bf2_to_f2(uint32_t u) {
    float2 r;
    r.x = __uint_as_float(u << 16);         // low ushort  = even col
    r.y = __uint_as_float(u & 0xffff0000u); // high ushort = odd col
    return r;
}

__device__ __forceinline__ ushort_t f2bf(float f) {
    uint32_t u = __float_as_uint(f);
    u = (u + 0x7fffu + ((u >> 16) & 1u)) >> 16;   // RNE
    return (ushort_t)u;
}

// ---------------------------------------------------------------------------
// K0: build WT[n][k] bf16 = concat(W_loop | B0..B3) transposed. 81920 elems.
// ---------------------------------------------------------------------------
__global__ __launch_bounds__(256) void k_prep(
    const float* __restrict__ Wl, const float* __restrict__ bases,
    ushort_t* __restrict__ WT)
{
    const int i = blockIdx.x * 256 + threadIdx.x;
    if (i >= 640 * 128) return;
    const int n = i >> 7, k = i & 127;
    float v;
    if (n < 128) v = Wl[k * 128 + n];
    else         v = bases[(size_t)((n >> 7) - 1) * 16384 + k * 128 + (n & 127)];
    WT[i] = f2bf(v);
}

// ---------------------------------------------------------------------------
// K1: bf16 MFMA GEMM, B-register-resident (16x16x32 verified layouts:
//   A: m=lane&15, k=quad*8+j ; B: n=lane&15, k=quad*8+j ; D: col=m, row=quad*4+reg)
// Block = 128 rows x 320 cols; grid (391, 2). 4 waves, wave owns 5 col-tiles;
// B loaded ONCE to regs (80 VGPR), then 8 row-chunks of 16: 4 ds_read_b128 +
// 20 MFMA + stores. X fetched exactly once; stores interleave with compute.
// ---------------------------------------------------------------------------
__global__ __launch_bounds__(256) void k_gemm(
    const float* __restrict__ X, const ushort_t* __restrict__ WT,
    const float* __restrict__ bl, float* __restrict__ acc,
    ushort_t* __restrict__ H2)
{
    __shared__ ushort_t As[128][136];
    const int tid = threadIdx.x;
    const int row0 = blockIdx.x * 128;
    const int ch = blockIdx.y;           // col half: 0 -> cols 0..319, 1 -> 320..639

    // stage: 128 rows x 128 f32 -> bf16 LDS. 2 threads/row, 64 floats each.
    {
        const int r = tid >> 1;
        const int c0 = (tid & 1) * 64;
        const int row = row0 + r;
        if (row < NN) {
            const float4* p = (const float4*)(X + (size_t)row * 128 + c0);
#pragma unroll
            for (int i = 0; i < 8; ++i) {
                const float4 a = p[2 * i], b = p[2 * i + 1];
                ushort_t t8[8] = { f2bf(a.x), f2bf(a.y), f2bf(a.z), f2bf(a.w),
                                   f2bf(b.x), f2bf(b.y), f2bf(b.z), f2bf(b.w) };
                *(uint4*)&As[r][c0 + i * 8] = *(const uint4*)t8;
            }
        } else {
            const uint4 z = make_uint4(0, 0, 0, 0);
#pragma unroll
            for (int i = 0; i < 8; ++i) *(uint4*)&As[r][c0 + i * 8] = z;
        }
    }
    __syncthreads();

    const int lane = tid & 63;
    const int w = tid >> 6;
    const int m = lane & 15;
    const int quad = lane >> 4;
    const int tbase = ch * 20 + w * 5;   // global 16-col tile index (0..39)

    // B fragments: 5 tiles x 4 K-chunks, register-resident for the whole block
    bf16x8 bfrag[5][4];
#pragma unroll
    for (int t = 0; t < 5; ++t) {
        const ushort_t* bp = WT + ((size_t)((tbase + t) * 16 + m)) * 128 + quad * 8;
#pragma unroll
        for (int kc = 0; kc < 4; ++kc)
            bfrag[t][kc] = __builtin_bit_cast(bf16x8, *(const ushort8*)(bp + kc * 32));
    }

    // per-tile destination metadata (tiles never straddle a 128-col segment)
    int seg_[5], cb_[5];
    float blv_[5];
#pragma unroll
    for (int t = 0; t < 5; ++t) {
        const int col = (tbase + t) * 16 + m;
        seg_[t] = col >> 7;
        cb_[t] = col & 127;
        blv_[t] = (seg_[t] == 0) ? bl[cb_[t]] : 0.f;
    }

    for (int chunk = 0; chunk < 8; ++chunk) {
        const int arow = chunk * 16 + m;
        bf16x8 afrag[4];
#pragma unroll
        for (int kc = 0; kc < 4; ++kc)
            afrag[kc] = __builtin_bit_cast(bf16x8,
                *(const ushort8*)&As[arow][kc * 32 + quad * 8]);

        f32x4 c[5];
#pragma unroll
        for (int t = 0; t < 5; ++t)
#pragma unroll
            for (int i = 0; i < 4; ++i) c[t][i] = 0.f;

#pragma unroll
        for (int kc = 0; kc < 4; ++kc)
#pragma unroll
            for (int t = 0; t < 5; ++t)
                c[t] = __builtin_amdgcn_mfma_f32_16x16x32_bf16(
                    afrag[kc], bfrag[t][kc], c[t], 0, 0, 0);

        // epilogue for this 16-row chunk. D: col=m, row=quad*4+reg
        const int rowb = row0 + chunk * 16 + quad * 4;
#pragma unroll
        for (int t = 0; t < 5; ++t) {
            if (seg_[t] == 0) {
#pragma unroll
                for (int r = 0; r < 4; ++r) {
                    const int row = rowb + r;
                    if (row < NN) acc[(size_t)row * 128 + cb_[t]] = c[t][r] + blv_[t];
                }
            } else {
                const int b = seg_[t] - 1;
#pragma unroll
                for (int r = 0; r < 4; ++r) {
                    const int row = rowb + r;
                    if (row < NN) H2[(size_t)row * 512 + b * 128 + cb_[t]] = f2bf(c[t][r]);
                }
            }
        }
    }
}

// ---------------------------------------------------------------------------
// K2: histogram of dst -> cnt
// ---------------------------------------------------------------------------
__global__ __launch_bounds__(256) void k_hist(
    const int* __restrict__ eidx, int* __restrict__ cnt)
{
    const int* __restrict__ dst = eidx + NE;
    for (int e = blockIdx.x * 256 + threadIdx.x; e < NE; e += gridDim.x * 256)
        atomicAdd(cnt + dst[e], 1);
}

// ---------------------------------------------------------------------------
// K3a/b/c: exclusive scan of cnt -> curs
// ---------------------------------------------------------------------------
__global__ __launch_bounds__(256) void k_scan1(
    const int* __restrict__ cnt, int* __restrict__ curs, int* __restrict__ bsum)
{
    __shared__ int sh[256];
    const int tid = threadIdx.x;
    const int i0 = blockIdx.x * 512 + tid * 2;
    const int v0 = (i0 < NN) ? cnt[i0] : 0;
    const int v1 = (i0 + 1 < NN) ? cnt[i0 + 1] : 0;
    int s = v0 + v1;
    sh[tid] = s;
    __syncthreads();
#pragma unroll
    for (int off = 1; off < 256; off <<= 1) {
        int t = (tid >= off) ? sh[tid - off] : 0;
        __syncthreads();
        sh[tid] += t;
        __syncthreads();
    }
    const int excl = sh[tid] - s;
    if (i0 < NN) curs[i0] = excl;
    if (i0 + 1 < NN) curs[i0 + 1] = excl + v0;
    if (tid == 255) bsum[blockIdx.x] = sh[255];
}

__global__ __launch_bounds__(128) void k_scan2(
    const int* __restrict__ bsum, int* __restrict__ bscan, int nblk)
{
    __shared__ int sh[128];
    const int tid = threadIdx.x;
    int v = (tid < nblk) ? bsum[tid] : 0;
    sh[tid] = v;
    __syncthreads();
#pragma unroll
    for (int off = 1; off < 128; off <<= 1) {
        int t = (tid >= off) ? sh[tid - off] : 0;
        __syncthreads();
        sh[tid] += t;
        __syncthreads();
    }
    if (tid < nblk) bscan[tid] = sh[tid] - v;
}

__global__ __launch_bounds__(256) void k_scan3(
    int* __restrict__ curs, const int* __restrict__ bscan)
{
    const int add = bscan[blockIdx.x];
    const int i0 = blockIdx.x * 512 + threadIdx.x * 2;
    if (i0 < NN) curs[i0] += add;
    if (i0 + 1 < NN) curs[i0 + 1] += add;
}

// ---------------------------------------------------------------------------
// K4: scatter edges into CSR slots. epack = src | (type<<16).
// ---------------------------------------------------------------------------
__global__ __launch_bounds__(256) void k_scatter(
    const int* __restrict__ eidx, const int* __restrict__ etype,
    int* __restrict__ curs, uint32_t* __restrict__ epack)
{
    const int* __restrict__ src = eidx;
    const int* __restrict__ dst = eidx + NE;
    for (int e = blockIdx.x * 256 + threadIdx.x; e < NE; e += gridDim.x * 256) {
        const int d = dst[e];
        const int pos = atomicAdd(curs + d, 1);
        epack[pos] = (uint32_t)src[e] | ((uint32_t)etype[e] << 16);
    }
}

// ---------------------------------------------------------------------------
// K5: gather. One wave per dst node, 2 cols/lane, zero atomics.
// H2 layout [node][base][col]: 4 dword loads per edge per lane. 4-edge unroll.
// ---------------------------------------------------------------------------
__device__ __forceinline__ void edge_accum(
    uint32_t ep, const ushort_t* __restrict__ H2,
    const float* __restrict__ coeff, int lane, float& m0, float& m1)
{
    const int s = ep & 0xffff;
    const int t = ep >> 16;
    const float4 cw = *(const float4*)(coeff + t * 4);
    const ushort_t* hp = H2 + (size_t)s * 512 + lane * 2;
    const uint32_t v0 = *(const uint32_t*)(hp);
    const uint32_t v1 = *(const uint32_t*)(hp + 128);
    const uint32_t v2 = *(const uint32_t*)(hp + 256);
    const uint32_t v3 = *(const uint32_t*)(hp + 384);
    const float2 p0 = bf2_to_f2(v0);
    const float2 p1 = bf2_to_f2(v1);
    const float2 p2 = bf2_to_f2(v2);
    const float2 p3 = bf2_to_f2(v3);
    m0 += cw.x * p0.x + cw.y * p1.x + cw.z * p2.x + cw.w * p3.x;
    m1 += cw.x * p0.y + cw.y * p1.y + cw.z * p2.y + cw.w * p3.y;
}

__global__ __launch_bounds__(256) void k_gather(
    const ushort_t* __restrict__ H2, const uint32_t* __restrict__ epack,
    const int* __restrict__ cnt, const int* __restrict__ curs,
    const float* __restrict__ coeff, float* __restrict__ acc)
{
    const int lane = threadIdx.x & 63;
    const int d = (blockIdx.x * 256 + threadIdx.x) >> 6;
    if (d >= NN) return;

    const int n = cnt[d];
    const int end = curs[d];          // post-scatter: end offset
    int j = end - n;

    float m0 = 0.f, m1 = 0.f;
    for (; j + 3 < end; j += 4) {
        const uint32_t e0 = epack[j];
        const uint32_t e1 = epack[j + 1];
        const uint32_t e2 = epack[j + 2];
        const uint32_t e3 = epack[j + 3];
        edge_accum(e0, H2, coeff, lane, m0, m1);
        edge_accum(e1, H2, coeff, lane, m0, m1);
        edge_accum(e2, H2, coeff, lane, m0, m1);
        edge_accum(e3, H2, coeff, lane, m0, m1);
    }
    for (; j < end; ++j) edge_accum(epack[j], H2, coeff, lane, m0, m1);

    const float inv = 1.0f / (float)((n > 0) ? n : 1);
    float* p = acc + (size_t)d * 128 + lane * 2;
    float2 a = *(float2*)p;
    a.x = (a.x + m0) * inv;
    a.y = (a.y + m1) * inv;
    *(float2*)p = a;
}

// ---------------------------------------------------------------------------
// K6: copy acc -> out, accumulate per-column sum/sumsq.
// ---------------------------------------------------------------------------
__global__ __launch_bounds__(256) void k_stats(
    const float* __restrict__ acc, float* __restrict__ out,
    float* __restrict__ colsum, float* __restrict__ colsq)
{
    const int tid = threadIdx.x;
    const int g = blockIdx.x * 256 + tid;
    const int col = g & 127;
    const int rstep = (gridDim.x * 256) >> 7;
    float s = 0.f, q = 0.f;
    for (int r = g >> 7; r < NN; r += rstep) {
        const float v = acc[(size_t)r * 128 + col];
        out[(size_t)r * 128 + col] = v;
        s += v; q += v * v;
    }
    __shared__ float s1[256], s2[256];
    s1[tid] = s; s2[tid] = q;
    __syncthreads();
    if (tid < 128) {
        atomicAdd(colsum + tid, s1[tid] + s1[tid + 128]);
        atomicAdd(colsq + tid, s2[tid] + s2[tid + 128]);
    }
}

// ---------------------------------------------------------------------------
// K7: BatchNorm (batch stats) + ReLU, in place on d_out.
// ---------------------------------------------------------------------------
__global__ __launch_bounds__(256) void k_bn_relu(
    float* __restrict__ out, const float* __restrict__ colsum,
    const float* __restrict__ colsq, const float* __restrict__ gamma,
    const float* __restrict__ beta)
{
    __shared__ float sc[128], sh[128];
    const int tid = threadIdx.x;
    if (tid < 128) {
        const float mean = colsum[tid] * (1.0f / NN);
        const float var = colsq[tid] * (1.0f / NN) - mean * mean;
        const float g = gamma[tid] * rsqrtf(var + 1e-5f);
        sc[tid] = g;
        sh[tid] = beta[tid] - mean * g;
    }
    __syncthreads();
    const int total = NN * 32;
    for (int i = blockIdx.x * 256 + tid; i < total; i += gridDim.x * 256) {
        const int c = (i & 31) << 2;
        float4 v = *(float4*)(out + (size_t)i * 4);
        v.x = fmaxf(fmaf(v.x, sc[c + 0], sh[c + 0]), 0.f);
        v.y = fmaxf(fmaf(v.y, sc[c + 1], sh[c + 1]), 0.f);
        v.z = fmaxf(fmaf(v.z, sc[c + 2], sh[c + 2]), 0.f);
        v.w = fmaxf(fmaf(v.w, sc[c + 3], sh[c + 3]), 0.f);
        *(float4*)(out + (size_t)i * 4) = v;
    }
}

extern "C" void kernel_launch(void* const* d_in, const int* in_sizes, int n_in,
                              void* d_out, int out_size, void* d_ws, size_t ws_size,
                              hipStream_t stream)
{
    const float* X      = (const float*)d_in[0];
    const float* bases  = (const float*)d_in[1];
    const float* coeff  = (const float*)d_in[2];
    const float* Wl     = (const float*)d_in[3];
    const float* bl     = (const float*)d_in[4];
    const float* gamma  = (const float*)d_in[5];
    const float* beta   = (const float*)d_in[6];
    const int*   eidx   = (const int*)d_in[7];
    const int*   etype  = (const int*)d_in[8];
    float* out = (float*)d_out;

    float* ws = (float*)d_ws;
    float*    acc    = ws + ACC_OFF;
    ushort_t* H2     = (ushort_t*)(ws + H2_OFF);
    int*      cnt    = (int*)(ws + CNT_OFF);
    int*      curs   = (int*)(ws + CUR_OFF);
    int*      bsum   = (int*)(ws + BSUM_OFF);
    int*      bscan  = (int*)(ws + BSCN_OFF);
    float*    colsum = ws + CS_OFF;
    float*    colsq  = ws + CSQ_OFF;
    uint32_t* epack  = (uint32_t*)d_out;                  // scatter->gather window
    ushort_t* WT     = (ushort_t*)(out + WT_OUT_OFF);     // prep->gemm window

    // zero cnt, curs, bsum, bscan, colsum, colsq
    hipMemsetAsync(cnt, 0, (CSQ_OFF + 128 - CNT_OFF) * sizeof(float), stream);

    const int nblk_scan = (NN + 511) / 512;   // 98

    k_prep<<<(640 * 128 + 255) / 256, 256, 0, stream>>>(Wl, bases, WT);
    k_gemm<<<dim3((NN + 127) / 128, 2), 256, 0, stream>>>(X, WT, bl, acc, H2);
    k_hist<<<512, 256, 0, stream>>>(eidx, cnt);
    k_scan1<<<nblk_scan, 256, 0, stream>>>(cnt, curs, bsum);
    k_scan2<<<1, 128, 0, stream>>>(bsum, bscan, nblk_scan);
    k_scan3<<<nblk_scan, 256, 0, stream>>>(curs, bscan);
    k_scatter<<<512, 256, 0, stream>>>(eidx, etype, curs, epack);
    k_gather<<<(NN + 3) / 4, 256, 0, stream>>>(H2, epack, cnt, curs, coeff, acc);
    k_stats<<<512, 256, 0, stream>>>(acc, out, colsum, colsq);
    k_bn_relu<<<1024, 256, 0, stream>>>(out, colsum, colsq, gamma, beta);
}

// Round 7
// 305.942 us; speedup vs baseline: 2.5899x; 1.0512x over previous
//
#include <hip/hip_runtime.h>
#include <cstdint>

#define NN 50000
#define NE 600000

typedef unsigned short ushort_t;
typedef __bf16 bf16_t;
typedef __attribute__((ext_vector_type(8))) bf16_t bf16x8;
typedef __attribute__((ext_vector_type(8))) ushort_t ushort8;
typedef __attribute__((ext_vector_type(4))) float f32x4;

// ---- ws layout (float offsets) ----
// acc  : [NN][128] f32                        @ 0
// G    : [NN][4 bases][128 cols] bf16         @ 6,400,000   (25.6M ushorts)
// cnt  : [NN] i32                             @ 19,200,000
// curs : [NN] i32                             @ 19,250,000
// bsum/bscan : [128]+[128] i32                @ 19,300,000 / 19,300,128
// colsum/colsq : [128]+[128] f32              @ 19,300,256 / 19,300,384
// ---- d_out transients (all dead before k_stats writes out) ----
// epack: [NE] u32          @ 0         (scatter -> gather)
// Xbf  : [NN][128] bf16    @ 600,064   (gemm1 -> gather)
// WlT  : [128][128] bf16   @ 3,900,000 (prep -> gemm1)
// WBT  : [128][512] bf16   @ 3,910,000 (prep -> gemm2)
#define ACC_OFF  0ul
#define G_OFF    6400000ul
#define CNT_OFF  19200000ul
#define CUR_OFF  19250000ul
#define BSUM_OFF 19300000ul
#define BSCN_OFF 19300128ul
#define CS_OFF   19300256ul
#define CSQ_OFF  19300384ul
#define EPACK_OUT_OFF 0ul
#define XBF_OUT_OFF   600064ul
#define WLT_OUT_OFF   3900000ul
#define WBT_OUT_OFF   3910000ul

__device__ __forceinline__ float2 bf2_to_f2(uint32_t u) {
    float2 r;
    r.x = __uint_as_float(u << 16);         // low ushort  = even col
    r.y = __uint_as_float(u & 0xffff0000u); // high ushort = odd col
    return r;
}

__device__ __forceinline__ ushort_t f2bf(float f) {
    uint32_t u = __float_as_uint(f);
    u = (u + 0x7fffu + ((u >> 16) & 1u)) >> 16;   // RNE
    return (ushort_t)u;
}

__device__ __forceinline__ uint32_t f2bf2(float x, float y) {
    return (uint32_t)f2bf(x) | ((uint32_t)f2bf(y) << 16);
}

// ---------------------------------------------------------------------------
// K0: build WlT[n][k]=Wl[k][n] (16384) and WBT[n][b*128+i]=bases[b][i][n] (65536).
// ---------------------------------------------------------------------------
__global__ __launch_bounds__(256) void k_prep(
    const float* __restrict__ Wl, const float* __restrict__ bases,
    ushort_t* __restrict__ WlT, ushort_t* __restrict__ WBT)
{
    const int i = blockIdx.x * 256 + threadIdx.x;
    if (i < 16384) {
        const int n = i >> 7, k = i & 127;
        WlT[i] = f2bf(Wl[k * 128 + n]);
    } else if (i < 81920) {
        const int j = i - 16384;          // n*512 + b*128 + ii
        const int n = j >> 9;
        const int r = j & 511;
        const int b = r >> 7, ii = r & 127;
        WBT[j] = f2bf(bases[(size_t)b * 16384 + ii * 128 + n]);
    }
}

// ---------------------------------------------------------------------------
// K1: selfloop GEMM acc = X @ Wl + bl  (128x128 block, B reg-resident),
// AND emit Xbf (bf16 copy of X) from the staging pass.
// 16x16x32 layouts: A m=lane&15,k=quad*8+j; B n=lane&15,k=quad*8+j;
// D col=lane&15,row=quad*4+reg.
// ---------------------------------------------------------------------------
__global__ __launch_bounds__(256) void k_gemm1(
    const float* __restrict__ X, const ushort_t* __restrict__ WlT,
    const float* __restrict__ bl, float* __restrict__ acc,
    ushort_t* __restrict__ Xbf)
{
    __shared__ ushort_t As[128][136];
    const int tid = threadIdx.x;
    const int row0 = blockIdx.x * 128;

    // stage 128 rows x 128 f32 -> bf16 LDS + write Xbf. 2 thr/row, 64 floats each.
    {
        const int r = tid >> 1;
        const int c0 = (tid & 1) * 64;
        const int row = row0 + r;
        if (row < NN) {
            const float4* p = (const float4*)(X + (size_t)row * 128 + c0);
            uint4* xq = (uint4*)(Xbf + (size_t)row * 128 + c0);
#pragma unroll
            for (int i = 0; i < 8; ++i) {
                const float4 a = p[2 * i], b = p[2 * i + 1];
                ushort_t t8[8] = { f2bf(a.x), f2bf(a.y), f2bf(a.z), f2bf(a.w),
                                   f2bf(b.x), f2bf(b.y), f2bf(b.z), f2bf(b.w) };
                const uint4 v = *(const uint4*)t8;
                *(uint4*)&As[r][c0 + i * 8] = v;
                xq[i] = v;
            }
        } else {
            const uint4 z = make_uint4(0, 0, 0, 0);
#pragma unroll
            for (int i = 0; i < 8; ++i) *(uint4*)&As[r][c0 + i * 8] = z;
        }
    }
    __syncthreads();

    const int lane = tid & 63;
    const int w = tid >> 6;
    const int m = lane & 15;
    const int quad = lane >> 4;

    bf16x8 bfrag[2][4];
    int cb[2];
    float blv[2];
#pragma unroll
    for (int t = 0; t < 2; ++t) {
        const int col = w * 32 + t * 16 + m;
        cb[t] = col;
        blv[t] = bl[col];
        const ushort_t* bp = WlT + (size_t)col * 128 + quad * 8;
#pragma unroll
        for (int kc = 0; kc < 4; ++kc)
            bfrag[t][kc] = __builtin_bit_cast(bf16x8, *(const ushort8*)(bp + kc * 32));
    }

    for (int chunk = 0; chunk < 8; ++chunk) {
        const int arow = chunk * 16 + m;
        bf16x8 afrag[4];
#pragma unroll
        for (int kc = 0; kc < 4; ++kc)
            afrag[kc] = __builtin_bit_cast(bf16x8,
                *(const ushort8*)&As[arow][kc * 32 + quad * 8]);

        f32x4 c[2];
#pragma unroll
        for (int t = 0; t < 2; ++t)
#pragma unroll
            for (int i = 0; i < 4; ++i) c[t][i] = 0.f;

#pragma unroll
        for (int kc = 0; kc < 4; ++kc)
#pragma unroll
            for (int t = 0; t < 2; ++t)
                c[t] = __builtin_amdgcn_mfma_f32_16x16x32_bf16(
                    afrag[kc], bfrag[t][kc], c[t], 0, 0, 0);

        const int rowb = row0 + chunk * 16 + quad * 4;
#pragma unroll
        for (int t = 0; t < 2; ++t)
#pragma unroll
            for (int r = 0; r < 4; ++r) {
                const int row = rowb + r;
                if (row < NN) acc[(size_t)row * 128 + cb[t]] = c[t][r] + blv[t];
            }
    }
}

// ---------------------------------------------------------------------------
// K2: histogram of dst -> cnt
// ---------------------------------------------------------------------------
__global__ __launch_bounds__(256) void k_hist(
    const int* __restrict__ eidx, int* __restrict__ cnt)
{
    const int* __restrict__ dst = eidx + NE;
    for (int e = blockIdx.x * 256 + threadIdx.x; e < NE; e += gridDim.x * 256)
        atomicAdd(cnt + dst[e], 1);
}

// ---------------------------------------------------------------------------
// K3a/b/c: exclusive scan of cnt -> curs
// ---------------------------------------------------------------------------
__global__ __launch_bounds__(256) void k_scan1(
    const int* __restrict__ cnt, int* __restrict__ curs, int* __restrict__ bsum)
{
    __shared__ int sh[256];
    const int tid = threadIdx.x;
    const int i0 = blockIdx.x * 512 + tid * 2;
    const int v0 = (i0 < NN) ? cnt[i0] : 0;
    const int v1 = (i0 + 1 < NN) ? cnt[i0 + 1] : 0;
    int s = v0 + v1;
    sh[tid] = s;
    __syncthreads();
#pragma unroll
    for (int off = 1; off < 256; off <<= 1) {
        int t = (tid >= off) ? sh[tid - off] : 0;
        __syncthreads();
        sh[tid] += t;
        __syncthreads();
    }
    const int excl = sh[tid] - s;
    if (i0 < NN) curs[i0] = excl;
    if (i0 + 1 < NN) curs[i0 + 1] = excl + v0;
    if (tid == 255) bsum[blockIdx.x] = sh[255];
}

__global__ __launch_bounds__(128) void k_scan2(
    const int* __restrict__ bsum, int* __restrict__ bscan, int nblk)
{
    __shared__ int sh[128];
    const int tid = threadIdx.x;
    int v = (tid < nblk) ? bsum[tid] : 0;
    sh[tid] = v;
    __syncthreads();
#pragma unroll
    for (int off = 1; off < 128; off <<= 1) {
        int t = (tid >= off) ? sh[tid - off] : 0;
        __syncthreads();
        sh[tid] += t;
        __syncthreads();
    }
    if (tid < nblk) bscan[tid] = sh[tid] - v;
}

__global__ __launch_bounds__(256) void k_scan3(
    int* __restrict__ curs, const int* __restrict__ bscan)
{
    const int add = bscan[blockIdx.x];
    const int i0 = blockIdx.x * 512 + threadIdx.x * 2;
    if (i0 < NN) curs[i0] += add;
    if (i0 + 1 < NN) curs[i0 + 1] += add;
}

// ---------------------------------------------------------------------------
// K4: scatter edges into CSR slots. epack = src | (type<<16).
// ---------------------------------------------------------------------------
__global__ __launch_bounds__(256) void k_scatter(
    const int* __restrict__ eidx, const int* __restrict__ etype,
    int* __restrict__ curs, uint32_t* __restrict__ epack)
{
    const int* __restrict__ src = eidx;
    const int* __restrict__ dst = eidx + NE;
    for (int e = blockIdx.x * 256 + threadIdx.x; e < NE; e += gridDim.x * 256) {
        const int d = dst[e];
        const int pos = atomicAdd(curs + d, 1);
        epack[pos] = (uint32_t)src[e] | ((uint32_t)etype[e] << 16);
    }
}

// ---------------------------------------------------------------------------
// K5: gather RAW X rows (256 B/edge): G_b[d] = sum_{e->d} c[t_e,b] * xbf[src_e].
// One wave per dst, lane owns cols (2*lane, 2*lane+1); 8 f32 accumulators.
// ---------------------------------------------------------------------------
__device__ __forceinline__ void edge_accum(
    uint32_t ep, const ushort_t* __restrict__ Xbf,
    const float* __restrict__ coeff, int lane,
    float2& m0, float2& m1, float2& m2, float2& m3)
{
    const int s = ep & 0xffff;
    const int t = ep >> 16;
    const float4 cw = *(const float4*)(coeff + t * 4);
    const uint32_t xv = *(const uint32_t*)(Xbf + (size_t)s * 128 + lane * 2);
    const float2 x = bf2_to_f2(xv);
    m0.x += cw.x * x.x; m0.y += cw.x * x.y;
    m1.x += cw.y * x.x; m1.y += cw.y * x.y;
    m2.x += cw.z * x.x; m2.y += cw.z * x.y;
    m3.x += cw.w * x.x; m3.y += cw.w * x.y;
}

__global__ __launch_bounds__(256) void k_gather(
    const ushort_t* __restrict__ Xbf, const uint32_t* __restrict__ epack,
    const int* __restrict__ cnt, const int* __restrict__ curs,
    const float* __restrict__ coeff, ushort_t* __restrict__ G)
{
    const int lane = threadIdx.x & 63;
    const int d = (blockIdx.x * 256 + threadIdx.x) >> 6;
    if (d >= NN) return;

    const int n = cnt[d];
    const int end = curs[d];          // post-scatter: end offset
    int j = end - n;

    float2 m0 = {0.f, 0.f}, m1 = {0.f, 0.f}, m2 = {0.f, 0.f}, m3 = {0.f, 0.f};
    for (; j + 3 < end; j += 4) {
        const uint32_t e0 = epack[j];
        const uint32_t e1 = epack[j + 1];
        const uint32_t e2 = epack[j + 2];
        const uint32_t e3 = epack[j + 3];
        edge_accum(e0, Xbf, coeff, lane, m0, m1, m2, m3);
        edge_accum(e1, Xbf, coeff, lane, m0, m1, m2, m3);
        edge_accum(e2, Xbf, coeff, lane, m0, m1, m2, m3);
        edge_accum(e3, Xbf, coeff, lane, m0, m1, m2, m3);
    }
    for (; j < end; ++j) edge_accum(epack[j], Xbf, coeff, lane, m0, m1, m2, m3);

    uint32_t* gp = (uint32_t*)(G + (size_t)d * 512) + lane;
    gp[0]   = f2bf2(m0.x, m0.y);
    gp[64]  = f2bf2(m1.x, m1.y);
    gp[128] = f2bf2(m2.x, m2.y);
    gp[192] = f2bf2(m3.x, m3.y);
}

// ---------------------------------------------------------------------------
// K6: msg GEMM acc = (acc + G @ B_cat) / deg.  K=512, block 128x128, 4 waves,
// wave = 2 col-tiles; B reg-resident (2x16 frags); A direct from L2-hot G.
// ---------------------------------------------------------------------------
__global__ __launch_bounds__(256) void k_gemm2(
    const ushort_t* __restrict__ G, const ushort_t* __restrict__ WBT,
    const int* __restrict__ cnt, float* __restrict__ acc)
{
    const int tid = threadIdx.x;
    const int row0 = blockIdx.x * 128;
    const int lane = tid & 63;
    const int w = tid >> 6;
    const int m = lane & 15;
    const int quad = lane >> 4;

    bf16x8 bfrag[2][16];
    int cb[2];
#pragma unroll
    for (int t = 0; t < 2; ++t) {
        const int col = w * 32 + t * 16 + m;
        cb[t] = col;
        const ushort_t* bp = WBT + (size_t)col * 512 + quad * 8;
#pragma unroll
        for (int kc = 0; kc < 16; ++kc)
            bfrag[t][kc] = __builtin_bit_cast(bf16x8, *(const ushort8*)(bp + kc * 32));
    }

    for (int chunk = 0; chunk < 8; ++chunk) {
        int arow = row0 + chunk * 16 + m;
        if (arow >= NN) arow = NN - 1;   // clamp (stores are guarded)
        const ushort_t* ap = G + (size_t)arow * 512 + quad * 8;

        f32x4 c[2];
#pragma unroll
        for (int t = 0; t < 2; ++t)
#pragma unroll
            for (int i = 0; i < 4; ++i) c[t][i] = 0.f;

#pragma unroll
        for (int half = 0; half < 2; ++half) {
            bf16x8 afrag[8];
#pragma unroll
            for (int kc = 0; kc < 8; ++kc)
                afrag[kc] = __builtin_bit_cast(bf16x8,
                    *(const ushort8*)(ap + (half * 8 + kc) * 32));
#pragma unroll
            for (int kc = 0; kc < 8; ++kc) {
                c[0] = __builtin_amdgcn_mfma_f32_16x16x32_bf16(
                    afrag[kc], bfrag[0][half * 8 + kc], c[0], 0, 0, 0);
                c[1] = __builtin_amdgcn_mfma_f32_16x16x32_bf16(
                    afrag[kc], bfrag[1][half * 8 + kc], c[1], 0, 0, 0);
            }
        }

        const int rowb = row0 + chunk * 16 + quad * 4;
#pragma unroll
        for (int r = 0; r < 4; ++r) {
            const int row = rowb + r;
            if (row < NN) {
                const int dg = cnt[row];
                const float inv = 1.0f / (float)((dg > 0) ? dg : 1);
                float* p0 = acc + (size_t)row * 128;
                p0[cb[0]] = (p0[cb[0]] + c[0][r]) * inv;
                p0[cb[1]] = (p0[cb[1]] + c[1][r]) * inv;
            }
        }
    }
}

// ---------------------------------------------------------------------------
// K7: copy acc -> out, accumulate per-column sum/sumsq.
// ---------------------------------------------------------------------------
__global__ __launch_bounds__(256) void k_stats(
    const float* __restrict__ acc, float* __restrict__ out,
    float* __restrict__ colsum, float* __restrict__ colsq)
{
    const int tid = threadIdx.x;
    const int g = blockIdx.x * 256 + tid;
    const int col = g & 127;
    const int rstep = (gridDim.x * 256) >> 7;
    float s = 0.f, q = 0.f;
    for (int r = g >> 7; r < NN; r += rstep) {
        const float v = acc[(size_t)r * 128 + col];
        out[(size_t)r * 128 + col] = v;
        s += v; q += v * v;
    }
    __shared__ float s1[256], s2[256];
    s1[tid] = s; s2[tid] = q;
    __syncthreads();
    if (tid < 128) {
        atomicAdd(colsum + tid, s1[tid] + s1[tid + 128]);
        atomicAdd(colsq + tid, s2[tid] + s2[tid + 128]);
    }
}

// ---------------------------------------------------------------------------
// K8: BatchNorm (batch stats) + ReLU, in place on d_out.
// ---------------------------------------------------------------------------
__global__ __launch_bounds__(256) void k_bn_relu(
    float* __restrict__ out, const float* __restrict__ colsum,
    const float* __restrict__ colsq, const float* __restrict__ gamma,
    const float* __restrict__ beta)
{
    __shared__ float sc[128], sh[128];
    const int tid = threadIdx.x;
    if (tid < 128) {
        const float mean = colsum[tid] * (1.0f / NN);
        const float var = colsq[tid] * (1.0f / NN) - mean * mean;
        const float g = gamma[tid] * rsqrtf(var + 1e-5f);
        sc[tid] = g;
        sh[tid] = beta[tid] - mean * g;
    }
    __syncthreads();
    const int total = NN * 32;
    for (int i = blockIdx.x * 256 + tid; i < total; i += gridDim.x * 256) {
        const int c = (i & 31) << 2;
        float4 v = *(float4*)(out + (size_t)i * 4);
        v.x = fmaxf(fmaf(v.x, sc[c + 0], sh[c + 0]), 0.f);
        v.y = fmaxf(fmaf(v.y, sc[c + 1], sh[c + 1]), 0.f);
        v.z = fmaxf(fmaf(v.z, sc[c + 2], sh[c + 2]), 0.f);
        v.w = fmaxf(fmaf(v.w, sc[c + 3], sh[c + 3]), 0.f);
        *(float4*)(out + (size_t)i * 4) = v;
    }
}

extern "C" void kernel_launch(void* const* d_in, const int* in_sizes, int n_in,
                              void* d_out, int out_size, void* d_ws, size_t ws_size,
                              hipStream_t stream)
{
    const float* X      = (const float*)d_in[0];
    const float* bases  = (const float*)d_in[1];
    const float* coeff  = (const float*)d_in[2];
    const float* Wl     = (const float*)d_in[3];
    const float* bl     = (const float*)d_in[4];
    const float* gamma  = (const float*)d_in[5];
    const float* beta   = (const float*)d_in[6];
    const int*   eidx   = (const int*)d_in[7];
    const int*   etype  = (const int*)d_in[8];
    float* out = (float*)d_out;

    float* ws = (float*)d_ws;
    float*    acc    = ws + ACC_OFF;
    ushort_t* G      = (ushort_t*)(ws + G_OFF);
    int*      cnt    = (int*)(ws + CNT_OFF);
    int*      curs   = (int*)(ws + CUR_OFF);
    int*      bsum   = (int*)(ws + BSUM_OFF);
    int*      bscan  = (int*)(ws + BSCN_OFF);
    float*    colsum = ws + CS_OFF;
    float*    colsq  = ws + CSQ_OFF;
    uint32_t* epack  = (uint32_t*)(out + EPACK_OUT_OFF);
    ushort_t* Xbf    = (ushort_t*)(out + XBF_OUT_OFF);
    ushort_t* WlT    = (ushort_t*)(out + WLT_OUT_OFF);
    ushort_t* WBT    = (ushort_t*)(out + WBT_OUT_OFF);

    // zero cnt, curs, bsum, bscan, colsum, colsq
    hipMemsetAsync(cnt, 0, (CSQ_OFF + 128 - CNT_OFF) * sizeof(float), stream);

    const int nblk_scan = (NN + 511) / 512;   // 98

    k_prep<<<320, 256, 0, stream>>>(Wl, bases, WlT, WBT);
    k_gemm1<<<(NN + 127) / 128, 256, 0, stream>>>(X, WlT, bl, acc, Xbf);
    k_hist<<<512, 256, 0, stream>>>(eidx, cnt);
    k_scan1<<<nblk_scan, 256, 0, stream>>>(cnt, curs, bsum);
    k_scan2<<<1, 128, 0, stream>>>(bsum, bscan, nblk_scan);
    k_scan3<<<nblk_scan, 256, 0, stream>>>(curs, bscan);
    k_scatter<<<512, 256, 0, stream>>>(eidx, etype, curs, epack);
    k_gather<<<(NN + 3) / 4, 256, 0, stream>>>(Xbf, epack, cnt, curs, coeff, G);
    k_gemm2<<<(NN + 127) / 128, 256, 0, stream>>>(G, WBT, cnt, acc);
    k_stats<<<512, 256, 0, stream>>>(acc, out, colsum, colsq);
    k_bn_relu<<<1024, 256, 0, stream>>>(out, colsum, colsq, gamma, beta);
}